// Round 17
// baseline (326.701 us; speedup 1.0000x reference)
//
#include <hip/hip_runtime.h>

// GAT layer, N=8192, D=256. R17 = R16 + 3-blocks/CU attn retry:
//  - KVB=32 single-buffer sH -> LDS ~40KB (3x40=120K << 160K; R15's 54.3K
//    x3 missed the pool by <1KB). __launch_bounds__(256,3), VGPR cap 85.
//  - NSPLIT=4 (1024 blocks) so >=768 blocks exist to fill 3/CU; NPART=4
//    fused combine in gemm_final.
//  - cvt_split + featT fused into prep_kernel (saves 8MB feat re-read).

typedef __attribute__((ext_vector_type(8))) _Float16 f16x8;
typedef __attribute__((ext_vector_type(4))) short s16x4;
typedef __attribute__((ext_vector_type(4))) float f32x4;

#define NN 8192
#define DD 256
#define NSPLIT 4
#define NPART 4
#define CHUNK (NN / NSPLIT)
#define KVB 32
#define BM 32
#define NT (CHUNK / KVB)

#define MFMA16(a, b, c) __builtin_amdgcn_mfma_f32_16x16x32_f16(a, b, c, 0, 0, 0)
#define BAR_LGKM() asm volatile("s_waitcnt lgkmcnt(0)\n\ts_barrier" ::: "memory")
#define BAR_VM() asm volatile("s_waitcnt vmcnt(0)\n\ts_barrier" ::: "memory")

__device__ __forceinline__ short f2h(float f) {
  union { _Float16 h; short s; } u; u.h = (_Float16)f; return u.s;
}
__device__ __forceinline__ float h2f(short b) {
  union { short s; _Float16 h; } u; u.s = b; return (float)u.h;
}

typedef __attribute__((address_space(3))) unsigned lds_u32;
typedef const __attribute__((address_space(1))) unsigned glb_u32;
__device__ __forceinline__ void gl2lds16(const void* g, void* l) {
  __builtin_amdgcn_global_load_lds((glb_u32*)g, (lds_u32*)l, 16, 0, 0);
}

// fused: featHi/featLo (elementwise) + fT (transpose via LDS), one feat read
__global__ __launch_bounds__(256) void prep_kernel(const float* __restrict__ feat,
                                                   short* __restrict__ hi,
                                                   short* __restrict__ lo,
                                                   short* __restrict__ fT) {
  __shared__ float tile[32][33];
  const int i0 = blockIdx.x * 32, c0 = blockIdx.y * 32;
  const int r = threadIdx.x >> 5, c = threadIdx.x & 31;
#pragma unroll
  for (int p = 0; p < 4; ++p) {
    size_t idx = (size_t)(i0 + p * 8 + r) * DD + c0 + c;
    float f = feat[idx];
    tile[p * 8 + r][c] = f;
    short h = f2h(f);
    hi[idx] = h;
    lo[idx] = f2h(f - h2f(h));
  }
  __syncthreads();
#pragma unroll
  for (int p = 0; p < 4; ++p)
    fT[(size_t)(c0 + p * 8 + r) * NN + i0 + c] = f2h(tile[c][p * 8 + r]);
}

// All 4 weight transposes in one launch. blockIdx.y selects the matrix.
__global__ __launch_bounds__(256) void transpose_all_kernel(
    const float* __restrict__ W, const float* __restrict__ a12,
    const float* __restrict__ W1, const float* __restrict__ W2,
    short* __restrict__ WTh, short* __restrict__ WTl,
    short* __restrict__ A12Th, short* __restrict__ A12Tl,
    short* __restrict__ W1T, short* __restrict__ W2T) {
  const int r = blockIdx.x, c = threadIdx.x;
  const int which = blockIdx.y;
  const float* src = (which == 0) ? W : (which == 1) ? a12 : (which == 2) ? W1 : W2;
  float f = src[r * DD + c];
  short h = f2h(f);
  if (which == 0) {
    WTh[c * DD + r] = h; WTl[c * DD + r] = f2h(f - h2f(h));
  } else if (which == 1) {
    A12Th[c * DD + r] = h; A12Tl[c * DD + r] = f2h(f - h2f(h));
  } else if (which == 2) {
    W1T[c * DD + r] = h;
  } else {
    W2T[c * DD + r] = h;
  }
}

// C[64x64 tile] = A @ BT^T over K=256, fp16 MFMA (+split options)
__global__ __launch_bounds__(256) void gemm_kernel(
    const short* __restrict__ Ahi, const short* __restrict__ Alo,
    const short* __restrict__ BThi, const short* __restrict__ BTlo,
    short* __restrict__ outH) {
  const int lane = threadIdx.x & 63;
  const int w = threadIdx.x >> 6;
  const int l15 = lane & 15;
  const int koff = (lane >> 4) * 8;
  const int row0 = blockIdx.x * 64 + w * 16;
  const int col0 = blockIdx.y * 64;
  f32x4 acc[4] = {};
  const int aoff = (row0 + l15) * DD + koff;
#pragma unroll
  for (int kk = 0; kk < 8; ++kk) {
    f16x8 ah = *(const f16x8*)(Ahi + aoff + kk * 32);
#pragma unroll
    for (int cf = 0; cf < 4; ++cf) {
      int boff = (col0 + cf * 16 + l15) * DD + kk * 32 + koff;
      f16x8 bh = *(const f16x8*)(BThi + boff);
      acc[cf] = MFMA16(ah, bh, acc[cf]);
      if (Alo) {
        f16x8 al = *(const f16x8*)(Alo + aoff + kk * 32);
        acc[cf] = MFMA16(al, bh, acc[cf]);
      }
      if (BTlo) {
        f16x8 bl = *(const f16x8*)(BTlo + boff);
        acc[cf] = MFMA16(ah, bl, acc[cf]);
      }
    }
  }
  const int crow = row0 + (lane >> 4) * 4;
#pragma unroll
  for (int cf = 0; cf < 4; ++cf) {
    int col = col0 + cf * 16 + l15;
#pragma unroll
    for (int r = 0; r < 4; ++r)
      outH[(crow + r) * DD + col] = f2h(acc[cf][r]);
  }
}

// Final GEMM with fused NPART-way combine.
__global__ __launch_bounds__(256) void gemm_final_kernel(
    const short* __restrict__ featHi, const short* __restrict__ W1T,
    const short* __restrict__ numPart, const float* __restrict__ mPart,
    const float* __restrict__ lPart, const short* __restrict__ W2T,
    float* __restrict__ outF) {
  const int lane = threadIdx.x & 63;
  const int w = threadIdx.x >> 6;
  const int l15 = lane & 15;
  const int koff = (lane >> 4) * 8;
  const int row0 = blockIdx.x * 64 + w * 16;
  const int col0 = blockIdx.y * 64;
  const int arow = row0 + l15;
  float m[NPART], l[NPART];
  float ms = -__builtin_inff();
#pragma unroll
  for (int i = 0; i < NPART; ++i) {
    m[i] = mPart[i * NN + arow];
    l[i] = lPart[i * NN + arow];
    ms = fmaxf(ms, m[i]);
  }
  float wgt[NPART], denom = 0.f;
#pragma unroll
  for (int i = 0; i < NPART; ++i) {
    wgt[i] = __expf(m[i] - ms);
    denom += l[i] * wgt[i];
  }
  float invd = 1.f / denom;
  f16x8 vc[NPART];
#pragma unroll
  for (int i = 0; i < NPART; ++i) {
    _Float16 ci = (_Float16)(wgt[i] * invd);
#pragma unroll
    for (int j = 0; j < 8; ++j) vc[i][j] = ci;
  }
  f32x4 acc[4] = {};
  const int aoff = arow * DD + koff;
#pragma unroll
  for (int kk = 0; kk < 8; ++kk) {
    f16x8 ah = *(const f16x8*)(featHi + aoff + kk * 32);
    f16x8 a2 = {};
#pragma unroll
    for (int i = 0; i < NPART; ++i) {
      f16x8 pi = *(const f16x8*)(numPart + (size_t)i * NN * DD + aoff + kk * 32);
      a2 = a2 + pi * vc[i];
    }
#pragma unroll
    for (int cf = 0; cf < 4; ++cf) {
      int boff = (col0 + cf * 16 + l15) * DD + kk * 32 + koff;
      acc[cf] = MFMA16(ah, *(const f16x8*)(W1T + boff), acc[cf]);
      acc[cf] = MFMA16(a2, *(const f16x8*)(W2T + boff), acc[cf]);
    }
  }
  const int crow = row0 + (lane >> 4) * 4;
#pragma unroll
  for (int cf = 0; cf < 4; ++cf) {
    int col = col0 + cf * 16 + l15;
#pragma unroll
    for (int r = 0; r < 4; ++r) {
      float v = acc[cf][r];
      v = (v > 0.f) ? v : expm1f(v);
      outF[(crow + r) * DD + col] = v;
    }
  }
}

// ax[i] = h[i,:]·a1, ay[i] = h[i,:]·a2  (h fp16)
__global__ __launch_bounds__(256) void axay_kernel(const short* __restrict__ hF,
                                                   const float* __restrict__ a1,
                                                   const float* __restrict__ a2,
                                                   float* __restrict__ ax,
                                                   float* __restrict__ ay) {
  const int lane = threadIdx.x & 63;
  const int w = threadIdx.x >> 6;
  const int row = blockIdx.x * 4 + w;
  float s1 = 0.f, s2 = 0.f;
#pragma unroll
  for (int j = 0; j < 4; ++j) {
    int k = lane * 4 + j;
    float hv = h2f(hF[row * DD + k]);
    s1 += hv * a1[k];
    s2 += hv * a2[k];
  }
#pragma unroll
  for (int m = 1; m < 64; m <<= 1) {
    s1 += __shfl_xor(s1, m);
    s2 += __shfl_xor(s2, m);
  }
  if (lane == 0) { ax[row] = s1; ay[row] = s2; }
}

// Flash attention, KVB=32, 3 blocks/CU target. 32q x 32kv, 4 waves.
__global__ __launch_bounds__(256, 3) void attn_kernel(
    const short* __restrict__ gF, const short* __restrict__ hF,
    const short* __restrict__ fT, const float* __restrict__ ax,
    const float* __restrict__ ay, const int* __restrict__ adj,
    short* __restrict__ numPart, float* __restrict__ mPart,
    float* __restrict__ lPart) {
  __shared__ short sG[BM * DD];     // 16384B g tile (512B rows, XOR-swizzled)
  __shared__ short sH[KVB * DD];    // 16384B h tile (512B rows, XOR-swizzled)
  __shared__ float sS[BM][36];      // 4608B S exchange
  __shared__ short sP[BM][40];      // 2560B P exchange
  __shared__ float sScale[BM];      // 128B
  // total ~40KB -> 3 blocks/CU (120KB) with ample margin

  const int tid = threadIdx.x;
  const int lane = tid & 63;
  const int w = tid >> 6;
  const int wr = w >> 1, sp = w & 1;
  const int l15 = lane & 15;
  const int q0 = lane >> 4;
  const int crow = q0 * 4;

  // 1024 blocks: chunk c -> XCD pair {2c,2c+1}
  const int bid = blockIdx.x;
  const int chunk = (bid & 7) >> 1;
  const int rowblk = ((bid >> 3) << 1) | (bid & 1);
  const int row0 = rowblk * BM;
  const int jbase = chunk * CHUNK;

  float ay4[4];
#pragma unroll
  for (int r = 0; r < 4; ++r) ay4[r] = ay[row0 + wr * 16 + crow + r];

#pragma unroll
  for (int R = 0; R < 4; ++R) {
    int dstb = R * 4096 + tid * 16;
    int lr = dstb >> 9;
    int srcb = (dstb & 511) ^ ((lr & 7) << 4);
    gl2lds16(gF + (row0 + lr) * DD + (srcb >> 1), (char*)sG + dstb);
  }
  auto stageH = [&](int jrow) {
#pragma unroll
    for (int R = 0; R < 4; ++R) {
      int dstb = R * 4096 + tid * 16;
      int lr = dstb >> 9;
      int srcb = (dstb & 511) ^ ((lr & 7) << 4);
      gl2lds16(hF + (jrow + lr) * DD + (srcb >> 1), (char*)sH + dstb);
    }
  };
  stageH(jbase);

  // adj/ax prefetch tile 0 (nt: streaming, no L2 pollution)
  const size_t adjrow = (size_t)(row0 + wr * 16 + crow) * NN;
  int a4[4];
  float axv;
  {
    int kb = jbase + sp * 16 + l15;
    axv = ax[kb];
#pragma unroll
    for (int r = 0; r < 4; ++r)
      a4[r] = __builtin_nontemporal_load(adj + adjrow + (size_t)r * NN + kb);
  }

  const int srow = tid >> 3;
  const int sc4 = (tid & 7) * 4;
  float m_run = -__builtin_inff();
  float l_run = 0.f;
  f32x4 accpv[2][4] = {};  // [rg][df]: rows rg*16+crow+r, dims w*64+df*16+l15

  BAR_VM();  // sG + sH(0) staged

  for (int t = 0; t < NT; ++t) {
    const int j0 = jbase + t * KVB;
    // ---- QK^T: 8 fp16 MFMA, A=g(sG) B=h(sH), 16q x 16kv per wave ----
    f32x4 acc = {};
    {
      const int lrA = wr * 16 + l15;
      const int rbA = lrA * 512, swzA = (lrA & 7) << 4;
      const int lrB = sp * 16 + l15;
      const int rbB = lrB * 512, swzB = (lrB & 7) << 4;
      __builtin_amdgcn_s_setprio(1);
#pragma unroll
      for (int kk = 0; kk < 8; ++kk) {
        const int slot = kk * 64 + q0 * 16;
        f16x8 ga = *(const f16x8*)((const char*)sG + rbA + (slot ^ swzA));
        f16x8 bh = *(const f16x8*)((const char*)sH + rbB + (slot ^ swzB));
        acc = MFMA16(ga, bh, acc);
      }
      __builtin_amdgcn_s_setprio(0);
    }
    // ---- mask + bias + leaky -> sS ----
#pragma unroll
    for (int r = 0; r < 4; ++r) {
      float v = acc[r] + axv + ay4[r];
      v = (v > 0.f) ? v : 0.2f * v;
      sS[wr * 16 + crow + r][sp * 16 + l15] = (a4[r] > 0) ? v : -9.0e15f;
    }
    BAR_LGKM();  // sS visible; sG/sH reads done
    // ---- vb -> adj(t+1) -> stage(t+1): PV's vmcnt waits only vb ----
    f16x8 vb[4];
#pragma unroll
    for (int df = 0; df < 4; ++df)
      vb[df] = *(const f16x8*)(fT + (size_t)(w * 64 + df * 16 + l15) * NN + j0 + q0 * 8);
    int a4n[4];
    float axn;
    {
      int jn = (t + 1 < NT) ? (j0 + KVB) : jbase;
      int kb = jn + sp * 16 + l15;
      axn = ax[kb];
#pragma unroll
      for (int r = 0; r < 4; ++r)
        a4n[r] = __builtin_nontemporal_load(adj + adjrow + (size_t)r * NN + kb);
    }
    if (t + 1 < NT) stageH(j0 + KVB);
    // ---- softmax: 8 threads/row, 4 cols each, 3 shfl ----
    {
      float4 sv = *(const float4*)(&sS[srow][sc4]);
      float tmax = fmaxf(fmaxf(sv.x, sv.y), fmaxf(sv.z, sv.w));
      tmax = fmaxf(tmax, __shfl_xor(tmax, 1));
      tmax = fmaxf(tmax, __shfl_xor(tmax, 2));
      tmax = fmaxf(tmax, __shfl_xor(tmax, 4));
      float m_new = fmaxf(m_run, tmax);
      float scale = __expf(m_run - m_new);
      float p0 = __expf(sv.x - m_new), p1 = __expf(sv.y - m_new);
      float p2 = __expf(sv.z - m_new), p3 = __expf(sv.w - m_new);
      float psum = (p0 + p1) + (p2 + p3);
      psum += __shfl_xor(psum, 1);
      psum += __shfl_xor(psum, 2);
      psum += __shfl_xor(psum, 4);
      l_run = l_run * scale + psum;
      m_run = m_new;
      union { short s[4]; s16x4 v; } pu;
      pu.s[0] = f2h(p0); pu.s[1] = f2h(p1); pu.s[2] = f2h(p2); pu.s[3] = f2h(p3);
      *(s16x4*)(&sP[srow][sc4]) = pu.v;
      if ((tid & 7) == 0) sScale[srow] = scale;
    }
    BAR_LGKM();  // sP/sScale visible
    // ---- PV: rescale + 8 MFMA ----
    {
      float4 sc0 = *(const float4*)(&sScale[crow]);
      float4 sc1 = *(const float4*)(&sScale[16 + crow]);
      const float* scp[2] = { &sc0.x, &sc1.x };
#pragma unroll
      for (int rg = 0; rg < 2; ++rg)
#pragma unroll
        for (int df = 0; df < 4; ++df)
#pragma unroll
          for (int r = 0; r < 4; ++r) accpv[rg][df][r] *= scp[rg][r];
      f16x8 pa0 = *(const f16x8*)(&sP[l15][q0 * 8]);
      f16x8 pa1 = *(const f16x8*)(&sP[16 + l15][q0 * 8]);
      __builtin_amdgcn_s_setprio(1);
#pragma unroll
      for (int df = 0; df < 4; ++df) {
        accpv[0][df] = MFMA16(pa0, vb[df], accpv[0][df]);
        accpv[1][df] = MFMA16(pa1, vb[df], accpv[1][df]);
      }
      __builtin_amdgcn_s_setprio(0);
    }
#pragma unroll
    for (int r = 0; r < 4; ++r) a4[r] = a4n[r];
    axv = axn;
    BAR_VM();  // stage(t+1)+vb done; sS/sP free
  }
  // ---- emit partials ----
  if ((tid & 7) == 0) {
    mPart[chunk * NN + row0 + srow] = m_run;
    lPart[chunk * NN + row0 + srow] = l_run;
  }
  short* np = numPart + (size_t)chunk * NN * DD;
#pragma unroll
  for (int rg = 0; rg < 2; ++rg)
#pragma unroll
    for (int df = 0; df < 4; ++df) {
      int col = w * 64 + df * 16 + l15;
#pragma unroll
      for (int r = 0; r < 4; ++r)
        np[(size_t)(row0 + rg * 16 + crow + r) * DD + col] = f2h(accpv[rg][df][r]);
    }
}

extern "C" void kernel_launch(void* const* d_in, const int* in_sizes, int n_in,
                              void* d_out, int out_size, void* d_ws, size_t ws_size,
                              hipStream_t stream) {
  const float* feat = (const float*)d_in[0];
  const int*   adj  = (const int*)d_in[1];
  const float* W    = (const float*)d_in[2];
  const float* a1   = (const float*)d_in[3];
  const float* a2   = (const float*)d_in[4];
  const float* a12  = (const float*)d_in[5];
  const float* W1   = (const float*)d_in[6];
  const float* W2   = (const float*)d_in[7];
  float* out = (float*)d_out;
  (void)in_sizes; (void)n_in; (void)out_size; (void)ws_size;

  char* ws = (char*)d_ws;
  size_t off = 0;
  auto alloc = [&](size_t b) { void* p = ws + off; off += (b + 255) & ~(size_t)255; return p; };
  short* featHi = (short*)alloc((size_t)NN * DD * 2);
  short* featLo = (short*)alloc((size_t)NN * DD * 2);
  short* fT     = (short*)alloc((size_t)NN * DD * 2);
  short* hF     = (short*)alloc((size_t)NN * DD * 2);
  short* gF     = (short*)alloc((size_t)NN * DD * 2);
  short* WTh    = (short*)alloc((size_t)DD * DD * 2);
  short* WTl    = (short*)alloc((size_t)DD * DD * 2);
  short* A12Th  = (short*)alloc((size_t)DD * DD * 2);
  short* A12Tl  = (short*)alloc((size_t)DD * DD * 2);
  short* W1T    = (short*)alloc((size_t)DD * DD * 2);
  short* W2T    = (short*)alloc((size_t)DD * DD * 2);
  float* axv    = (float*)alloc((size_t)NN * 4);
  float* ayv    = (float*)alloc((size_t)NN * 4);
  short* numPart = (short*)alloc((size_t)NPART * NN * DD * 2);
  float* mPart   = (float*)alloc((size_t)NPART * NN * 4);
  float* lPart   = (float*)alloc((size_t)NPART * NN * 4);

  prep_kernel<<<dim3(NN / 32, DD / 32), 256, 0, stream>>>(feat, featHi, featLo, fT);
  transpose_all_kernel<<<dim3(DD, 4), 256, 0, stream>>>(
      W, a12, W1, W2, WTh, WTl, A12Th, A12Tl, W1T, W2T);
  // h = feat @ W (split-fp16 3-term), stored fp16
  gemm_kernel<<<dim3(NN / 64, DD / 64), 256, 0, stream>>>(
      featHi, featLo, WTh, WTl, hF);
  // g = h @ a12 (2-term), stored fp16
  gemm_kernel<<<dim3(NN / 64, DD / 64), 256, 0, stream>>>(
      hF, nullptr, A12Th, A12Tl, gF);
  axay_kernel<<<NN / 4, 256, 0, stream>>>(hF, a1, a2, axv, ayv);
  attn_kernel<<<dim3((NN / BM) * NSPLIT), 256, 0, stream>>>(
      gF, hF, fT, axv, ayv, adj, numPart, mPart, lPart);
  // out = elu(feat@W1 + combine(numPart)@W2)  [combine fused]
  gemm_final_kernel<<<dim3(NN / 64, DD / 64), 256, 0, stream>>>(
      featHi, W1T, numPart, mPart, lPart, W2T, out);
}

// Round 18
// 268.972 us; speedup vs baseline: 1.2146x; 1.2146x over previous
//
#include <hip/hip_runtime.h>

// GAT layer, N=8192, D=256. R18 = R16 (champion, 297us) + error-budget diet:
//  - h/g pre-GEMMs single-term fp16 (split unnecessary: h/g STORAGE rounding
//    dominates logit noise; input rounding adds only ~4e-3 in quadrature).
//  - prep fusion (cvt+featT, one feat read), no featLo/WTl/A12Tl buffers.
//  - attn + fused-combine final GEMM byte-identical to R16.

typedef __attribute__((ext_vector_type(8))) _Float16 f16x8;
typedef __attribute__((ext_vector_type(4))) float f32x4;

#define NN 8192
#define DD 256
#define NSPLIT 2
#define NPART 2
#define CHUNK (NN / NSPLIT)
#define KVB 64
#define BM 32
#define NT (CHUNK / KVB)

#define MFMA16(a, b, c) __builtin_amdgcn_mfma_f32_16x16x32_f16(a, b, c, 0, 0, 0)
#define BAR_LGKM() asm volatile("s_waitcnt lgkmcnt(0)\n\ts_barrier" ::: "memory")
#define BAR_VM() asm volatile("s_waitcnt vmcnt(0)\n\ts_barrier" ::: "memory")

__device__ __forceinline__ short f2h(float f) {
  union { _Float16 h; short s; } u; u.h = (_Float16)f; return u.s;
}
__device__ __forceinline__ float h2f(short b) {
  union { short s; _Float16 h; } u; u.s = b; return (float)u.h;
}

typedef __attribute__((address_space(3))) unsigned lds_u32;
typedef const __attribute__((address_space(1))) unsigned glb_u32;
__device__ __forceinline__ void gl2lds16(const void* g, void* l) {
  __builtin_amdgcn_global_load_lds((glb_u32*)g, (lds_u32*)l, 16, 0, 0);
}

// fused: featH (elementwise f16) + fT (transpose via LDS), one feat read
__global__ __launch_bounds__(256) void prep_kernel(const float* __restrict__ feat,
                                                   short* __restrict__ fH,
                                                   short* __restrict__ fT) {
  __shared__ float tile[32][33];
  const int i0 = blockIdx.x * 32, c0 = blockIdx.y * 32;
  const int r = threadIdx.x >> 5, c = threadIdx.x & 31;
#pragma unroll
  for (int p = 0; p < 4; ++p) {
    size_t idx = (size_t)(i0 + p * 8 + r) * DD + c0 + c;
    float f = feat[idx];
    tile[p * 8 + r][c] = f;
    fH[idx] = f2h(f);
  }
  __syncthreads();
#pragma unroll
  for (int p = 0; p < 4; ++p)
    fT[(size_t)(c0 + p * 8 + r) * NN + i0 + c] = f2h(tile[c][p * 8 + r]);
}

// All 4 weight transposes (single fp16) in one launch.
__global__ __launch_bounds__(256) void transpose_all_kernel(
    const float* __restrict__ W, const float* __restrict__ a12,
    const float* __restrict__ W1, const float* __restrict__ W2,
    short* __restrict__ WT, short* __restrict__ A12T,
    short* __restrict__ W1T, short* __restrict__ W2T) {
  const int r = blockIdx.x, c = threadIdx.x;
  const int which = blockIdx.y;
  const float* src = (which == 0) ? W : (which == 1) ? a12 : (which == 2) ? W1 : W2;
  short* dst = (which == 0) ? WT : (which == 1) ? A12T : (which == 2) ? W1T : W2T;
  dst[c * DD + r] = f2h(src[r * DD + c]);
}

// C[64x64 tile] = A @ BT^T over K=256, single-term fp16 MFMA.
__global__ __launch_bounds__(256) void gemm_kernel(
    const short* __restrict__ A, const short* __restrict__ BT,
    short* __restrict__ outH) {
  const int lane = threadIdx.x & 63;
  const int w = threadIdx.x >> 6;
  const int l15 = lane & 15;
  const int koff = (lane >> 4) * 8;
  const int row0 = blockIdx.x * 64 + w * 16;
  const int col0 = blockIdx.y * 64;
  f32x4 acc[4] = {};
  const int aoff = (row0 + l15) * DD + koff;
#pragma unroll
  for (int kk = 0; kk < 8; ++kk) {
    f16x8 ah = *(const f16x8*)(A + aoff + kk * 32);
#pragma unroll
    for (int cf = 0; cf < 4; ++cf) {
      int boff = (col0 + cf * 16 + l15) * DD + kk * 32 + koff;
      acc[cf] = MFMA16(ah, *(const f16x8*)(BT + boff), acc[cf]);
    }
  }
  const int crow = row0 + (lane >> 4) * 4;
#pragma unroll
  for (int cf = 0; cf < 4; ++cf) {
    int col = col0 + cf * 16 + l15;
#pragma unroll
    for (int r = 0; r < 4; ++r)
      outH[(crow + r) * DD + col] = f2h(acc[cf][r]);
  }
}

// Final GEMM with fused NPART-way combine: out = elu(featH@W1T + hp@W2T),
// hp built on the fly from normalized partials in packed f16.
__global__ __launch_bounds__(256) void gemm_final_kernel(
    const short* __restrict__ featH, const short* __restrict__ W1T,
    const short* __restrict__ numPart, const float* __restrict__ mPart,
    const float* __restrict__ lPart, const short* __restrict__ W2T,
    float* __restrict__ outF) {
  const int lane = threadIdx.x & 63;
  const int w = threadIdx.x >> 6;
  const int l15 = lane & 15;
  const int koff = (lane >> 4) * 8;
  const int row0 = blockIdx.x * 64 + w * 16;
  const int col0 = blockIdx.y * 64;
  const int arow = row0 + l15;
  float m0 = mPart[arow], m1 = mPart[NN + arow];
  float l0 = lPart[arow], l1 = lPart[NN + arow];
  float ms = fmaxf(m0, m1);
  float w0 = __expf(m0 - ms), w1 = __expf(m1 - ms);
  float invd = 1.f / (l0 * w0 + l1 * w1);
  _Float16 ca = (_Float16)(w0 * invd), cb = (_Float16)(w1 * invd);
  f16x8 vca, vcb;
#pragma unroll
  for (int j = 0; j < 8; ++j) { vca[j] = ca; vcb[j] = cb; }
  const short* n0 = numPart;
  const short* n1 = numPart + (size_t)NN * DD;
  f32x4 acc[4] = {};
  const int aoff = arow * DD + koff;
#pragma unroll
  for (int kk = 0; kk < 8; ++kk) {
    f16x8 ah = *(const f16x8*)(featH + aoff + kk * 32);
    f16x8 p0 = *(const f16x8*)(n0 + aoff + kk * 32);
    f16x8 p1 = *(const f16x8*)(n1 + aoff + kk * 32);
    f16x8 a2 = p0 * vca + p1 * vcb;
#pragma unroll
    for (int cf = 0; cf < 4; ++cf) {
      int boff = (col0 + cf * 16 + l15) * DD + kk * 32 + koff;
      acc[cf] = MFMA16(ah, *(const f16x8*)(W1T + boff), acc[cf]);
      acc[cf] = MFMA16(a2, *(const f16x8*)(W2T + boff), acc[cf]);
    }
  }
  const int crow = row0 + (lane >> 4) * 4;
#pragma unroll
  for (int cf = 0; cf < 4; ++cf) {
    int col = col0 + cf * 16 + l15;
#pragma unroll
    for (int r = 0; r < 4; ++r) {
      float v = acc[cf][r];
      v = (v > 0.f) ? v : expm1f(v);
      outF[(crow + r) * DD + col] = v;
    }
  }
}

// ax[i] = h[i,:]·a1, ay[i] = h[i,:]·a2  (h fp16)
__global__ __launch_bounds__(256) void axay_kernel(const short* __restrict__ hF,
                                                   const float* __restrict__ a1,
                                                   const float* __restrict__ a2,
                                                   float* __restrict__ ax,
                                                   float* __restrict__ ay) {
  const int lane = threadIdx.x & 63;
  const int w = threadIdx.x >> 6;
  const int row = blockIdx.x * 4 + w;
  float s1 = 0.f, s2 = 0.f;
#pragma unroll
  for (int j = 0; j < 4; ++j) {
    int k = lane * 4 + j;
    float hv = h2f(hF[row * DD + k]);
    s1 += hv * a1[k];
    s2 += hv * a2[k];
  }
#pragma unroll
  for (int m = 1; m < 64; m <<= 1) {
    s1 += __shfl_xor(s1, m);
    s2 += __shfl_xor(s2, m);
  }
  if (lane == 0) { ax[row] = s1; ay[row] = s2; }
}

// Flash attention (R16/R14, unchanged): raw adj nt loads, KVB=64, fp16 QK.
__global__ __launch_bounds__(256, 2) void attn_kernel(
    const short* __restrict__ gF, const short* __restrict__ hF,
    const short* __restrict__ fT, const float* __restrict__ ax,
    const float* __restrict__ ay, const int* __restrict__ adj,
    short* __restrict__ numPart, float* __restrict__ mPart,
    float* __restrict__ lPart) {
  __shared__ short sG[BM * DD];     // 16KB g tile (512B rows, XOR-swizzled)
  __shared__ short sH[KVB * DD];    // 32KB h tile (512B rows, XOR-swizzled)
  __shared__ float sS[BM][68];      // 8.7KB S exchange
  __shared__ short sP[BM][72];      // 4.5KB P exchange (144B rows)
  __shared__ float sScale[BM];

  const int tid = threadIdx.x;
  const int lane = tid & 63;
  const int w = tid >> 6;
  const int wr = w >> 1, sp = w & 1;
  const int l15 = lane & 15;
  const int q0 = lane >> 4;
  const int crow = q0 * 4;

  const int bid = blockIdx.x;
  const int chunk = (bid & 7) >> 2;
  const int rowblk = (bid >> 3) * 4 + (bid & 3);
  const int row0 = rowblk * BM;
  const int jbase = chunk * CHUNK;

  float ay4[4];
#pragma unroll
  for (int r = 0; r < 4; ++r) ay4[r] = ay[row0 + wr * 16 + crow + r];

#pragma unroll
  for (int R = 0; R < 4; ++R) {
    int dstb = R * 4096 + tid * 16;
    int lr = dstb >> 9;
    int srcb = (dstb & 511) ^ ((lr & 7) << 4);
    gl2lds16(gF + (row0 + lr) * DD + (srcb >> 1), (char*)sG + dstb);
  }
  auto stageH = [&](int jrow) {
#pragma unroll
    for (int R = 0; R < 8; ++R) {
      int dstb = R * 4096 + tid * 16;
      int lr = dstb >> 9;
      int srcb = (dstb & 511) ^ ((lr & 7) << 4);
      gl2lds16(hF + (jrow + lr) * DD + (srcb >> 1), (char*)sH + dstb);
    }
  };
  stageH(jbase);

  const size_t adjrow = (size_t)(row0 + wr * 16 + crow) * NN;
  int a8[2][4];
  float ax2[2];
#pragma unroll
  for (int cf = 0; cf < 2; ++cf) {
    int kb = jbase + sp * 32 + cf * 16 + l15;
    ax2[cf] = ax[kb];
#pragma unroll
    for (int r = 0; r < 4; ++r)
      a8[cf][r] = __builtin_nontemporal_load(adj + adjrow + (size_t)r * NN + kb);
  }

  const int srow = tid >> 3;
  const int sc8 = (tid & 7) * 8;
  float m_run = -__builtin_inff();
  float l_run = 0.f;
  f32x4 accpv[2][4] = {};

  BAR_VM();

  for (int t = 0; t < NT; ++t) {
    const int j0 = jbase + t * KVB;
    f32x4 aA = {}, aB = {};
    {
      const int lrA = wr * 16 + l15;
      const int rbA = lrA * 512, swzA = (lrA & 7) << 4;
      const int lrB0 = sp * 32 + l15;
      const int rbB0 = lrB0 * 512, swzB0 = (lrB0 & 7) << 4;
      const int lrB1 = sp * 32 + 16 + l15;
      const int rbB1 = lrB1 * 512, swzB1 = (lrB1 & 7) << 4;
      __builtin_amdgcn_s_setprio(1);
#pragma unroll
      for (int kk = 0; kk < 8; ++kk) {
        const int slot = kk * 64 + q0 * 16;
        f16x8 ga = *(const f16x8*)((const char*)sG + rbA + (slot ^ swzA));
        f16x8 b0 = *(const f16x8*)((const char*)sH + rbB0 + (slot ^ swzB0));
        f16x8 b1 = *(const f16x8*)((const char*)sH + rbB1 + (slot ^ swzB1));
        aA = MFMA16(ga, b0, aA);
        aB = MFMA16(ga, b1, aB);
      }
      __builtin_amdgcn_s_setprio(0);
    }
#pragma unroll
    for (int cf = 0; cf < 2; ++cf) {
      const f32x4& ac = cf ? aB : aA;
#pragma unroll
      for (int r = 0; r < 4; ++r) {
        float v = ac[r] + ax2[cf] + ay4[r];
        v = (v > 0.f) ? v : 0.2f * v;
        sS[wr * 16 + crow + r][sp * 32 + cf * 16 + l15] =
            (a8[cf][r] > 0) ? v : -9.0e15f;
      }
    }
    BAR_LGKM();
    f16x8 vb[2][4];
#pragma unroll
    for (int ks = 0; ks < 2; ++ks)
#pragma unroll
      for (int df = 0; df < 4; ++df)
        vb[ks][df] = *(const f16x8*)(fT + (size_t)(w * 64 + df * 16 + l15) * NN +
                                     j0 + ks * 32 + q0 * 8);
    int a8n[2][4];
    float ax2n[2];
    {
      int jn = (t + 1 < NT) ? (j0 + KVB) : jbase;
#pragma unroll
      for (int cf = 0; cf < 2; ++cf) {
        int kb = jn + sp * 32 + cf * 16 + l15;
        ax2n[cf] = ax[kb];
#pragma unroll
        for (int r = 0; r < 4; ++r)
          a8n[cf][r] = __builtin_nontemporal_load(adj + adjrow + (size_t)r * NN + kb);
      }
    }
    if (t + 1 < NT) stageH(j0 + KVB);
    {
      float4 s0 = *(const float4*)(&sS[srow][sc8]);
      float4 s1 = *(const float4*)(&sS[srow][sc8 + 4]);
      float tmax = fmaxf(fmaxf(fmaxf(s0.x, s0.y), fmaxf(s0.z, s0.w)),
                         fmaxf(fmaxf(s1.x, s1.y), fmaxf(s1.z, s1.w)));
      tmax = fmaxf(tmax, __shfl_xor(tmax, 1));
      tmax = fmaxf(tmax, __shfl_xor(tmax, 2));
      tmax = fmaxf(tmax, __shfl_xor(tmax, 4));
      float m_new = fmaxf(m_run, tmax);
      float scale = __expf(m_run - m_new);
      float p[8];
      p[0] = __expf(s0.x - m_new); p[1] = __expf(s0.y - m_new);
      p[2] = __expf(s0.z - m_new); p[3] = __expf(s0.w - m_new);
      p[4] = __expf(s1.x - m_new); p[5] = __expf(s1.y - m_new);
      p[6] = __expf(s1.z - m_new); p[7] = __expf(s1.w - m_new);
      float psum = ((p[0] + p[1]) + (p[2] + p[3])) + ((p[4] + p[5]) + (p[6] + p[7]));
      psum += __shfl_xor(psum, 1);
      psum += __shfl_xor(psum, 2);
      psum += __shfl_xor(psum, 4);
      l_run = l_run * scale + psum;
      m_run = m_new;
      union { short s[8]; f16x8 v; } pu;
#pragma unroll
      for (int c = 0; c < 8; ++c) pu.s[c] = f2h(p[c]);
      *(f16x8*)(&sP[srow][sc8]) = pu.v;
      if ((tid & 7) == 0) sScale[srow] = scale;
    }
    BAR_LGKM();
    {
      float4 sc0 = *(const float4*)(&sScale[crow]);
      float4 sc1 = *(const float4*)(&sScale[16 + crow]);
      const float* scp[2] = { &sc0.x, &sc1.x };
#pragma unroll
      for (int rg = 0; rg < 2; ++rg)
#pragma unroll
        for (int df = 0; df < 4; ++df)
#pragma unroll
          for (int r = 0; r < 4; ++r) accpv[rg][df][r] *= scp[rg][r];
      __builtin_amdgcn_s_setprio(1);
#pragma unroll
      for (int ks = 0; ks < 2; ++ks) {
        f16x8 pa0 = *(const f16x8*)(&sP[l15][ks * 32 + q0 * 8]);
        f16x8 pa1 = *(const f16x8*)(&sP[16 + l15][ks * 32 + q0 * 8]);
#pragma unroll
        for (int df = 0; df < 4; ++df) {
          accpv[0][df] = MFMA16(pa0, vb[ks][df], accpv[0][df]);
          accpv[1][df] = MFMA16(pa1, vb[ks][df], accpv[1][df]);
        }
      }
      __builtin_amdgcn_s_setprio(0);
    }
#pragma unroll
    for (int cf = 0; cf < 2; ++cf) {
#pragma unroll
      for (int r = 0; r < 4; ++r) a8[cf][r] = a8n[cf][r];
      ax2[cf] = ax2n[cf];
    }
    BAR_VM();
  }
  if ((tid & 7) == 0) {
    mPart[chunk * NN + row0 + srow] = m_run;
    lPart[chunk * NN + row0 + srow] = l_run;
  }
  short* np = numPart + (size_t)chunk * NN * DD;
#pragma unroll
  for (int rg = 0; rg < 2; ++rg)
#pragma unroll
    for (int df = 0; df < 4; ++df) {
      int col = w * 64 + df * 16 + l15;
#pragma unroll
      for (int r = 0; r < 4; ++r)
        np[(size_t)(row0 + rg * 16 + crow + r) * DD + col] = f2h(accpv[rg][df][r]);
    }
}

extern "C" void kernel_launch(void* const* d_in, const int* in_sizes, int n_in,
                              void* d_out, int out_size, void* d_ws, size_t ws_size,
                              hipStream_t stream) {
  const float* feat = (const float*)d_in[0];
  const int*   adj  = (const int*)d_in[1];
  const float* W    = (const float*)d_in[2];
  const float* a1   = (const float*)d_in[3];
  const float* a2   = (const float*)d_in[4];
  const float* a12  = (const float*)d_in[5];
  const float* W1   = (const float*)d_in[6];
  const float* W2   = (const float*)d_in[7];
  float* out = (float*)d_out;
  (void)in_sizes; (void)n_in; (void)out_size; (void)ws_size;

  char* ws = (char*)d_ws;
  size_t off = 0;
  auto alloc = [&](size_t b) { void* p = ws + off; off += (b + 255) & ~(size_t)255; return p; };
  short* featH = (short*)alloc((size_t)NN * DD * 2);
  short* fT    = (short*)alloc((size_t)NN * DD * 2);
  short* hF    = (short*)alloc((size_t)NN * DD * 2);
  short* gF    = (short*)alloc((size_t)NN * DD * 2);
  short* WT    = (short*)alloc((size_t)DD * DD * 2);
  short* A12T  = (short*)alloc((size_t)DD * DD * 2);
  short* W1T   = (short*)alloc((size_t)DD * DD * 2);
  short* W2T   = (short*)alloc((size_t)DD * DD * 2);
  float* axv   = (float*)alloc((size_t)NN * 4);
  float* ayv   = (float*)alloc((size_t)NN * 4);
  short* numPart = (short*)alloc((size_t)NPART * NN * DD * 2);
  float* mPart   = (float*)alloc((size_t)NPART * NN * 4);
  float* lPart   = (float*)alloc((size_t)NPART * NN * 4);

  prep_kernel<<<dim3(NN / 32, DD / 32), 256, 0, stream>>>(feat, featH, fT);
  transpose_all_kernel<<<dim3(DD, 4), 256, 0, stream>>>(
      W, a12, W1, W2, WT, A12T, W1T, W2T);
  // h = feat @ W  (single fp16)
  gemm_kernel<<<dim3(NN / 64, DD / 64), 256, 0, stream>>>(featH, WT, hF);
  // g = h @ a12  (single fp16)
  gemm_kernel<<<dim3(NN / 64, DD / 64), 256, 0, stream>>>(hF, A12T, gF);
  axay_kernel<<<NN / 4, 256, 0, stream>>>(hF, a1, a2, axv, ayv);
  attn_kernel<<<dim3((NN / BM) * NSPLIT), 256, 0, stream>>>(
      gF, hF, fT, axv, ayv, adj, numPart, mPart, lPart);
  // out = elu(feat@W1 + combine(numPart)@W2)  [combine fused]
  gemm_final_kernel<<<dim3(NN / 64, DD / 64), 256, 0, stream>>>(
      featH, W1T, numPart, mPart, lPart, W2T, out);
}